// Round 6
// baseline (496.574 us; speedup 1.0000x reference)
//
#include <hip/hip_runtime.h>
#include <math.h>

typedef unsigned short u16;
typedef _Float16 half8 __attribute__((ext_vector_type(8)));
typedef float f32x4 __attribute__((ext_vector_type(4)));

#define BB 32
#define LL 700
#define HH 600
#define VV 2000
#define H4 2400

// ---- workspace byte offsets (16B aligned), K padded to 64-multiples ----
#define O_SCAT   0L            // f16 [22400][1280]: er 0:600(pad->640), att 640:1240(pad->1280)
#define O_LINH   57344000L     // f16 lin [22400][640]
#define O_R1     86016000L     // Ph f16 [2000][2400] -> sc16 f16 [22400][600]
#define O_ATTNH  112896000L    // f16 attn [32][700][704]
#define O_ERT    144435200L    // f16 erT [32][600][704]
#define O_EMBH   171468800L    // f16 emb [2000][640]
#define O_W2T    174028800L    // f16 W_relu^T [2400][640]
#define O_WLT    177100800L    // f16 W_lin^T [640][640]
#define O_WST    177920000L    // f16 W_sig^T [600][1280]
#define O_BL     179456000L    // fp32 b_lin padded [640]
#define O_PAD    179458560L    // fp32 [22400]
#define O_GATES  179624960L    // fp32 [32][2400]
#define O_WIHT   179932160L    // f16 [2400][1280]: W_ih^T | W_hh^T (k-padded halves)
#define O_WLOGT  186076160L    // f16 W_log^T [704][640]
#define O_XCAT   186977280L    // f16 [32][1280]: x | hid0 (k-padded halves)
#define O_HID16  187059200L    // f16 [32][640]
#define O_GLOG   187100160L    // fp32 [32][704]
#define O_XMEAN  187190272L    // fp32 [32][640] fused column-sum of sc (K6 epilogue)

__device__ inline u16 f2h(float x) { _Float16 h = (_Float16)x; u16 u; __builtin_memcpy(&u, &h, 2); return u; }
__device__ inline float h2f(u16 u) { _Float16 h; __builtin_memcpy(&h, &u, 2); return (float)h; }
__device__ inline float to_f(float x) { return x; }
__device__ inline float to_f(u16 x) { return h2f(x); }

// async global->LDS, 16B per lane, dest = wave-uniform base + lane*16
__device__ __forceinline__ void gll16(const u16* g, u16* l) {
    __builtin_amdgcn_global_load_lds(
        (__attribute__((address_space(1))) void*)g,
        (__attribute__((address_space(3))) void*)l, 16, 0, 0);
}

// ---------------------------------------------------------------------------
// R6 hgemm_v2: R2 core (128x128, BK=64, gll16 A-staging, syncthreads).
// Template BDIR=1 (K1/K3/K6: B = L2-resident weight matrix): B fragments
// read per-lane DIRECT from global each K-step -- removes 2 gll16 + 2
// ds_read_b128 per wave per K-step, halves barrier-protected LDS content,
// LDS 64->32KB (~3-4 blk/CU). Diagnostic for the ~5750cy/K-step plateau
// (R3: not barrier drain; R4: not wave count; R6 tests LDS/staging share).
// BDIR=0 (K4/K5: B = activations): fully staged as in R2.
//
// EPI=2 epilogue rework (R5 regression fix): ONE int div per block-half
// (bb0) + boundary compare instead of 32 divs/thread; interior wave-halves
// (rows within one batch, ~82% of tiles) combine the 4 q-lane partials via
// __shfl_xor(16/32) (4 lanes share fr -> same n -> exec-uniform group) and
// only q==0 issues the atomic: 4x fewer atomics.
// EPI: 1 = f16 C (+bias), 2 = f16 sigmoid(acc+bias)*gate + xmean column-sums
// ---------------------------------------------------------------------------
template<int EPI, int BDIR>
__global__ __launch_bounds__(512, 4) void hgemm_v2(
    const u16* __restrict__ A, const u16* __restrict__ B,
    u16* __restrict__ C16, const float* __restrict__ bias,
    const u16* __restrict__ gate, int ldg,
    float* __restrict__ xmean,
    int M, int N, int Kp, int lda, int ldb, int ldc,
    long sAz, long sBz, long sCz)
{
    const int bz = blockIdx.z;
    A += sAz * bz;  B += sBz * bz;  C16 += sCz * bz;

    __shared__ __align__(16) u16 As[16384];              // [2][128][64]
    __shared__ __align__(16) u16 Bs[BDIR ? 16 : 16384];  // staged only if !BDIR

    const int tid = threadIdx.x;

    // ---- XCD-aware swizzle ----
    const int nx = gridDim.x, ny = gridDim.y;
    const int bid = blockIdx.y * nx + blockIdx.x;
    const int fg  = ny >> 3;
    const int gsz = nx << 3;
    int m_i, n_i;
    if (bid < fg * gsz) {
        int g = bid / gsz, r = bid - g * gsz;
        m_i = (g << 3) + (r & 7);
        n_i = r >> 3;
    } else {
        m_i = bid / nx;
        n_i = bid - m_i * nx;
    }
    const int m0 = m_i << 7, n0 = n_i << 7;

    const int wave = tid >> 6, lane = tid & 63;
    const int fr = lane & 15, q = lane >> 4;           // frag row / k-quarter
    const int s0 = (q ^ (fr & 7)) << 3;                // swizzled slot, half 0 (elems)
    const int wm = (wave >> 2) << 6;                   // 0 or 64
    const int wn = (wave & 3) << 5;                    // 0,32,64,96

    // ---- A staging geometry (always) ----
    const int srow = lane >> 3;                        // 0..7 within 8-row group
    const int kx   = ((lane & 7) ^ srow) << 3;         // pre-swizzled source chunk (elems)
    int ra0 = m0 + (wave << 4) + srow;       if (ra0 > M - 1) ra0 = M - 1;
    int ra1 = m0 + (wave << 4) + 8 + srow;   if (ra1 > M - 1) ra1 = M - 1;
    const u16* gA0 = A + (long)ra0 * lda + kx;
    const u16* gA1 = A + (long)ra1 * lda + kx;
    u16* sAw = (u16*)As + (wave << 10);

    // ---- B path ----
    const u16 *gB0 = nullptr, *gB1 = nullptr;          // staged path
    u16* sBw = nullptr;
    const u16 *pB0 = nullptr, *pB1 = nullptr;          // direct path
    if (!BDIR) {
        int rb0 = n0 + (wave << 4) + srow;       if (rb0 > N - 1) rb0 = N - 1;
        int rb1 = n0 + (wave << 4) + 8 + srow;   if (rb1 > N - 1) rb1 = N - 1;
        gB0 = B + (long)rb0 * ldb + kx;
        gB1 = B + (long)rb1 * ldb + kx;
        sBw = (u16*)Bs + (wave << 10);
    } else {
        int nb0 = n0 + wn + fr;        if (nb0 > N - 1) nb0 = N - 1;
        int nb1 = n0 + wn + 16 + fr;   if (nb1 > N - 1) nb1 = N - 1;
        pB0 = B + (long)nb0 * ldb + (q << 3);
        pB1 = B + (long)nb1 * ldb + (q << 3);
    }

    f32x4 acc[4][2];
    #pragma unroll
    for (int i = 0; i < 4; ++i)
        #pragma unroll
        for (int j = 0; j < 2; ++j) acc[i][j] = (f32x4)0.f;

    const int nk = Kp >> 6;

    // prologue: stage tile 0 (syncthreads drains vmcnt -> visible to all waves)
    gll16(gA0, sAw);  gll16(gA1, sAw + 512);
    if (!BDIR) { gll16(gB0, sBw);  gll16(gB1, sBw + 512); }
    __syncthreads();

    for (int t = 0; t < nk; ++t) {
        const int cur = (t & 1) << 13;                 // 0 / 8192 elems
        if (t + 1 < nk) {
            const int nxt = cur ^ 8192;
            const long ko = (long)(t + 1) << 6;
            gll16(gA0 + ko, sAw + nxt);  gll16(gA1 + ko, sAw + nxt + 512);
            if (!BDIR) { gll16(gB0 + ko, sBw + nxt);  gll16(gB1 + ko, sBw + nxt + 512); }
        }
        #pragma unroll
        for (int half = 0; half < 2; ++half) {
            const int sh = s0 ^ (half << 5);           // slot ^= 4 for k half 1
            half8 af[4], bf[2];
            #pragma unroll
            for (int i = 0; i < 4; ++i)
                af[i] = *(const half8*)&As[cur + ((wm + (i << 4) + fr) << 6) + sh];
            if (BDIR) {
                const long ko = ((long)t << 6) + (half << 5);
                bf[0] = *(const half8*)(pB0 + ko);
                bf[1] = *(const half8*)(pB1 + ko);
            } else {
                #pragma unroll
                for (int j = 0; j < 2; ++j)
                    bf[j] = *(const half8*)&Bs[cur + ((wn + (j << 4) + fr) << 6) + sh];
            }
            #pragma unroll
            for (int i = 0; i < 4; ++i)
                #pragma unroll
                for (int j = 0; j < 2; ++j)
                    acc[i][j] = __builtin_amdgcn_mfma_f32_16x16x32_f16(af[i], bf[j], acc[i][j], 0, 0, 0);
        }
        __syncthreads();
    }

    // epilogue: C/D layout col=lane&15, row=(lane>>4)*4+r
    const int lr = (lane >> 4) << 2;

    int  bb0 = 0, bound = 0;
    bool interior = false;
    if (EPI == 2) {
        const int mlo = m0 + wm, mhi = m0 + wm + 63;
        bb0   = mlo / 700;                 // ONE division per thread
        bound = (bb0 + 1) * 700;
        interior = (mhi < bound) && (mhi < M);
    }

    #pragma unroll
    for (int j = 0; j < 2; ++j) {
        int n = n0 + wn + (j << 4) + fr;
        if (n >= N) continue;
        float bv = bias ? bias[n] : 0.f;

        if (EPI == 2 && interior) {
            float ps = 0.f;
            #pragma unroll
            for (int i = 0; i < 4; ++i) {
                #pragma unroll
                for (int r = 0; r < 4; ++r) {
                    int m = m0 + wm + (i << 4) + lr + r;
                    float v = acc[i][j][r] + bv;
                    float sg = 1.f / (1.f + expf(-v));
                    float scv = sg * h2f(gate[(long)m * ldg + n]);
                    C16[(long)m * ldc + n] = f2h(scv);
                    ps += scv;
                }
            }
            // combine the 4 q-lanes (same fr -> same n, exec-uniform group)
            ps += __shfl_xor(ps, 16);
            ps += __shfl_xor(ps, 32);
            if (q == 0) atomicAdd(&xmean[bb0 * 640 + n], ps);
        } else {
            float ps = 0.f;
            int   cb = -1;
            #pragma unroll
            for (int i = 0; i < 4; ++i) {
                #pragma unroll
                for (int r = 0; r < 4; ++r) {
                    int m = m0 + wm + (i << 4) + lr + r;
                    if (m >= M) continue;
                    long off = (long)m * ldc + n;
                    float v = acc[i][j][r] + bv;
                    if (EPI == 1) C16[off] = f2h(v);
                    if (EPI == 2) {
                        float sg = 1.f / (1.f + expf(-v));
                        float scv = sg * h2f(gate[(long)m * ldg + n]);
                        C16[off] = f2h(scv);
                        int b = (m < bound) ? bb0 : bb0 + 1;   // tile spans <=2 batches
                        if (b != cb) {
                            if (cb >= 0) atomicAdd(&xmean[cb * 640 + n], ps);
                            cb = b;  ps = 0.f;
                        }
                        ps += scv;
                    }
                }
            }
            if (EPI == 2 && cb >= 0) atomicAdd(&xmean[cb * 640 + n], ps);
        }
    }
}

// ---------------------------------------------------------------------------
// Skinny split-K GEMM for M=32 tails.
// ---------------------------------------------------------------------------
__global__ __launch_bounds__(256) void sgemm_k(
    const u16* __restrict__ A, const u16* __restrict__ B, float* __restrict__ C,
    int N, int Kseg, int lda, int ldb, int ldc)
{
    const int wave = threadIdx.x >> 6, lane = threadIdx.x & 63;
    const int fr = lane & 15, q8 = (lane >> 4) << 3;
    int n = blockIdx.x * 64 + wave * 16 + fr;
    int nc = (n < N) ? n : N - 1;
    const int k0 = blockIdx.y * Kseg;
    const u16* pa0 = A + (long)fr * lda + q8;          // m = fr
    const u16* pa1 = A + (long)(fr + 16) * lda + q8;   // m = fr+16
    const u16* pb  = B + (long)nc * ldb + q8;
    f32x4 acc0 = (f32x4)0.f, acc1 = (f32x4)0.f;
    #pragma unroll 2
    for (int k = k0; k < k0 + Kseg; k += 32) {
        half8 a0 = *(const half8*)(pa0 + k);
        half8 a1 = *(const half8*)(pa1 + k);
        half8 bv = *(const half8*)(pb + k);
        acc0 = __builtin_amdgcn_mfma_f32_16x16x32_f16(a0, bv, acc0, 0, 0, 0);
        acc1 = __builtin_amdgcn_mfma_f32_16x16x32_f16(a1, bv, acc1, 0, 0, 0);
    }
    if (n >= N) return;
    const int mr = (lane >> 4) << 2;       // row = (lane>>4)*4 + r
    #pragma unroll
    for (int r = 0; r < 4; ++r) {
        atomicAdd(&C[(long)(mr + r) * ldc + n], acc0[r]);
        atomicAdd(&C[(long)(mr + r + 16) * ldc + n], acc1[r]);
    }
}

// ---------------------------------------------------------------------------
// Fused prep kernel: all weight transposes + emb cast + bias pads + tail-C
// bias-inits + xmean zero-init in ONE launch. Grid (20,75,12).
// ---------------------------------------------------------------------------
__global__ __launch_bounds__(256) void prep_k(
    const float* __restrict__ emb, const float* __restrict__ W_relu,
    const float* __restrict__ W_lin, const float* __restrict__ W_sig,
    const float* __restrict__ W_ih, const float* __restrict__ W_hh,
    const float* __restrict__ W_log, const float* __restrict__ b_lin,
    const float* __restrict__ b_ih, const float* __restrict__ b_hh,
    const float* __restrict__ b_log,
    u16* __restrict__ embh, u16* __restrict__ w2t, u16* __restrict__ wlt,
    u16* __restrict__ wst, u16* __restrict__ wiht, u16* __restrict__ wlogt,
    float* __restrict__ bl640, float* __restrict__ gates, float* __restrict__ glog,
    float* __restrict__ xmean)
{
    __shared__ float t[32][33];
    const int z = blockIdx.z, bx = blockIdx.x, by = blockIdx.y;
    const int tid = threadIdx.x;

    if (z == 10) {
        int r = by * 32 + (tid >> 5), c = bx * 32 + (tid & 31);
        #pragma unroll
        for (int dy = 0; dy < 32; dy += 8) {
            int rr = r + dy;
            if (rr < VV && c < 640)
                embh[(long)rr * 640 + c] = (c < 600) ? f2h(emb[(long)rr * 600 + c]) : 0;
        }
        return;
    }
    if (z == 11) {
        long idx = ((long)bx * 75 + by) * 256 + tid;
        const long NG = 640 + (long)BB * H4;
        const long NL = NG + (long)BB * 704;
        const long NX = NL + (long)BB * 640;
        if (idx < 640) {
            bl640[idx] = (idx < 600) ? b_lin[idx] : 0.f;
        } else if (idx < NG) {
            long i = idx - 640;
            int n = (int)(i % H4);
            gates[i] = b_ih[n] + b_hh[n];
        } else if (idx < NL) {
            long i = idx - NG;
            int l = (int)(i % 704);
            glog[i] = (l < 700) ? b_log[l] : 0.f;
        } else if (idx < NX) {
            xmean[idx - NL] = 0.f;
        }
        return;
    }

    const float* s; u16* d;
    int R, C, lds_, ldo, Rpad, Cpad;
    if (z < 4)      { s = W_relu + 360000L * z; d = w2t + 384000L * z;
                      R = 600; C = 600; lds_ = 600; ldo = 640;  Rpad = 640; Cpad = 600; }
    else if (z == 4){ s = W_lin;           d = wlt;
                      R = 600; C = 600; lds_ = 600; ldo = 640;  Rpad = 640; Cpad = 640; }
    else if (z == 5){ s = W_sig;           d = wst;
                      R = 600; C = 600; lds_ = 600; ldo = 1280; Rpad = 640; Cpad = 600; }
    else if (z == 6){ s = W_sig + 360000;  d = wst + 640;
                      R = 600; C = 600; lds_ = 600; ldo = 1280; Rpad = 640; Cpad = 600; }
    else if (z == 7){ s = W_ih;            d = wiht;
                      R = 600; C = H4;  lds_ = H4;  ldo = 1280; Rpad = 640; Cpad = H4; }
    else if (z == 8){ s = W_hh;            d = wiht + 640;
                      R = 600; C = H4;  lds_ = H4;  ldo = 1280; Rpad = 640; Cpad = H4; }
    else            { s = W_log;           d = wlogt;
                      R = 600; C = 700; lds_ = 700; ldo = 640;  Rpad = 640; Cpad = 704; }

    int r0 = bx * 32, c0 = by * 32;
    if (r0 >= Rpad || c0 >= Cpad) return;
    int tx = tid & 31, ty = tid >> 5;
    #pragma unroll
    for (int dy = 0; dy < 32; dy += 8) {
        int r = r0 + ty + dy, c = c0 + tx;
        t[ty + dy][tx] = (r < R && c < C) ? s[(long)r * lds_ + c] : 0.f;
    }
    __syncthreads();
    #pragma unroll
    for (int dy = 0; dy < 32; dy += 8) {
        int c = c0 + ty + dy, r = r0 + tx;
        if (r < Rpad && c < Cpad) d[(long)c * ldo + r] = f2h(t[tx][ty + dy]);
    }
}

// ---------------------------------------------------------------------------
// transpose+cast (u16 source): kept for erT only.
// ---------------------------------------------------------------------------
template<typename T>
__global__ __launch_bounds__(256) void transpz_k(
    const T* __restrict__ s, u16* __restrict__ d,
    int R, int C, int lds_, int ldo, int Rpad, int Cpad, long zs_s, long zs_d)
{
    __shared__ float t[32][33];
    s += zs_s * blockIdx.z;  d += zs_d * blockIdx.z;
    int r0 = blockIdx.x * 32, c0 = blockIdx.y * 32;
    int tx = threadIdx.x & 31, ty = threadIdx.x >> 5;
    #pragma unroll
    for (int dy = 0; dy < 32; dy += 8) {
        int r = r0 + ty + dy, c = c0 + tx;
        t[ty + dy][tx] = (r < R && c < C) ? to_f(s[(long)r * lds_ + c]) : 0.f;
    }
    __syncthreads();
    #pragma unroll
    for (int dy = 0; dy < 32; dy += 8) {
        int c = c0 + ty + dy, r = r0 + tx;
        if (r < Rpad && c < Cpad) d[(long)c * ldo + r] = f2h(t[tx][ty + dy]);
    }
}

// er (2 h per thread, uint loads) into scat cols 0:600 + zero pads; pad flag
__global__ __launch_bounds__(320) void gather_relu_k(
    const int* __restrict__ rec, const u16* __restrict__ Ph,
    const float* __restrict__ b_relu, u16* __restrict__ scat, float* __restrict__ pad)
{
    int row = blockIdx.x;
    int t = threadIdx.x;
    int r0 = rec[row * 4 + 0], r1 = rec[row * 4 + 1];
    int r2 = rec[row * 4 + 2], r3 = rec[row * 4 + 3];
    u16* srow = scat + (long)row * 1280;
    if (t < 300) {
        int h = t << 1;
        uint a0 = *(const uint*)&Ph[(long)r0 * H4 + h];
        uint a1 = *(const uint*)&Ph[(long)r1 * H4 + 600 + h];
        uint a2 = *(const uint*)&Ph[(long)r2 * H4 + 1200 + h];
        uint a3 = *(const uint*)&Ph[(long)r3 * H4 + 1800 + h];
        float lo = b_relu[h]     + h2f((u16)a0) + h2f((u16)a1) + h2f((u16)a2) + h2f((u16)a3);
        float hi = b_relu[h + 1] + h2f((u16)(a0 >> 16)) + h2f((u16)(a1 >> 16))
                                 + h2f((u16)(a2 >> 16)) + h2f((u16)(a3 >> 16));
        uint o = (uint)f2h(fmaxf(lo, 0.f)) | ((uint)f2h(fmaxf(hi, 0.f)) << 16);
        *(uint*)&srow[h] = o;
    } else {
        int i = t - 300;
        *(uint*)&srow[600 + (i << 1)]  = 0;
        *(uint*)&srow[1240 + (i << 1)] = 0;
    }
    if (t == 0) {
        int mx = max(max(r0, r1), max(r2, r3));
        pad[row] = (mx == 0) ? 1.f : 0.f;
    }
}

// ---------------------------------------------------------------------------
// masked softmax, wave-per-row
// ---------------------------------------------------------------------------
__global__ __launch_bounds__(256) void softmax_w(u16* __restrict__ attnh,
                                                 const float* __restrict__ pad)
{
    const int wave = threadIdx.x >> 6, lane = threadIdx.x & 63;
    const int l = blockIdx.x * 4 + wave, b = blockIdx.y;
    u16* row = attnh + (long)b * (LL * 704) + (long)l * 704;
    const float* pb = pad + b * LL;
    const bool rowpad = pb[l] != 0.f;

    float v[12];
    float mx = -INFINITY;
    #pragma unroll
    for (int i = 0; i < 6; ++i) {
        int e0 = (lane + (i << 6)) << 1;
        float x0 = -INFINITY, x1 = -INFINITY;
        if (e0 < 704) {
            uint u = *(const uint*)&row[e0];
            if (e0 < LL && !(rowpad || e0 == l || pb[e0] != 0.f)) x0 = h2f((u16)u);
            int e1 = e0 + 1;
            if (e1 < LL && !(rowpad || e1 == l || pb[e1] != 0.f)) x1 = h2f((u16)(u >> 16));
        }
        v[2 * i] = x0;  v[2 * i + 1] = x1;
        mx = fmaxf(mx, fmaxf(x0, x1));
    }
    #pragma unroll
    for (int m = 32; m > 0; m >>= 1) mx = fmaxf(mx, __shfl_xor(mx, m));
    mx = fmaxf(mx, -1e30f);

    float sum = 0.f;
    #pragma unroll
    for (int i = 0; i < 12; ++i) { v[i] = expf(v[i] - mx); sum += v[i]; }
    #pragma unroll
    for (int m = 32; m > 0; m >>= 1) sum += __shfl_xor(sum, m);
    float inv = (sum > 0.f) ? 1.f / sum : 0.f;

    #pragma unroll
    for (int i = 0; i < 6; ++i) {
        int e0 = (lane + (i << 6)) << 1;
        if (e0 < 704) {
            uint u = (uint)f2h(v[2 * i] * inv) | ((uint)f2h(v[2 * i + 1] * inv) << 16);
            *(uint*)&row[e0] = u;
        }
    }
}

// fused xcat: x-gather (bx==3) + xmean finalize (bx<3) -> f16 xcat halves
__global__ __launch_bounds__(256) void xcat_k(const u16* __restrict__ sc,
                                              const int* __restrict__ index,
                                              const float* __restrict__ xmean,
                                              u16* __restrict__ xcat)
{
    int b = blockIdx.y;
    if (blockIdx.x == 3) {
        const u16* src = sc + ((long)b * LL + index[b]) * HH;
        u16* dst = xcat + b * 1280;
        for (int j = threadIdx.x; j < 1280; j += 256) {
            if (j < 600) dst[j] = src[j];
            else if (j < 640) dst[j] = 0;
            else if (j >= 1240) dst[j] = 0;
        }
        return;
    }
    int h = blockIdx.x * 256 + threadIdx.x;
    if (h >= HH) return;
    xcat[b * 1280 + 640 + h] = f2h(xmean[b * 640 + h] * (1.f / 700.f));
}

// cell = sigmoid(i)*tanh(g); hidden = sigmoid(o)*tanh(cell); + f16 hidden copy
__global__ void lstm_act_k(const float* __restrict__ gates,
                           float* __restrict__ out_hid, float* __restrict__ out_cell,
                           u16* __restrict__ hid16)
{
    int h = blockIdx.x * 256 + threadIdx.x;
    int b = blockIdx.y;
    if (h >= 640) return;
    if (h >= HH) { hid16[b * 640 + h] = 0; return; }
    const float* g = gates + b * H4;
    float gi = g[h], gg = g[1200 + h], go = g[1800 + h];
    float c = (1.f / (1.f + expf(-gi))) * tanhf(gg);
    float hd = (1.f / (1.f + expf(-go))) * tanhf(c);
    out_hid[b * HH + h] = hd;
    out_cell[b * HH + h] = c;
    hid16[b * 640 + h] = f2h(hd);
}

// masked log-softmax of glog row -> out
__global__ __launch_bounds__(256) void logsoftmax_k(const float* __restrict__ glog,
                                                    const float* __restrict__ pad,
                                                    const int* __restrict__ index,
                                                    float* __restrict__ out)
{
    int b = blockIdx.x;
    int t = threadIdx.x;
    int idx = index[b];
    __shared__ float red[256];
    float v[3];
    float mx = -INFINITY;
    #pragma unroll
    for (int ii = 0; ii < 3; ++ii) {
        int l = ii * 256 + t;
        float x = -INFINITY;
        if (l < LL && !(pad[b * LL + l] != 0.f || l == idx)) x = glog[b * 704 + l];
        v[ii] = x;
        mx = fmaxf(mx, x);
    }
    red[t] = mx; __syncthreads();
    for (int s = 128; s > 0; s >>= 1) {
        if (t < s) red[t] = fmaxf(red[t], red[t + s]);
        __syncthreads();
    }
    mx = red[0]; __syncthreads();
    float sum = 0.f;
    #pragma unroll
    for (int ii = 0; ii < 3; ++ii) {
        int l = ii * 256 + t;
        if (l < LL) sum += expf(v[ii] - mx);
    }
    red[t] = sum; __syncthreads();
    for (int s = 128; s > 0; s >>= 1) {
        if (t < s) red[t] += red[t + s];
        __syncthreads();
    }
    float lse = mx + logf(red[0]);
    #pragma unroll
    for (int ii = 0; ii < 3; ++ii) {
        int l = ii * 256 + t;
        if (l < LL) out[b * LL + l] = fmaxf(v[ii] - lse, -1e30f);
    }
}

// ---------------------------------------------------------------------------
extern "C" void kernel_launch(void* const* d_in, const int* in_sizes, int n_in,
                              void* d_out, int out_size, void* d_ws, size_t ws_size,
                              hipStream_t stream)
{
    const int*   records = (const int*)d_in[0];
    const int*   index   = (const int*)d_in[1];
    const float* emb     = (const float*)d_in[2];
    const float* W_relu  = (const float*)d_in[3];
    const float* b_relu  = (const float*)d_in[4];
    const float* W_lin   = (const float*)d_in[5];
    const float* b_lin   = (const float*)d_in[6];
    const float* W_sig   = (const float*)d_in[7];
    const float* b_sig   = (const float*)d_in[8];
    const float* W_ih    = (const float*)d_in[9];
    const float* W_hh    = (const float*)d_in[10];
    const float* b_ih    = (const float*)d_in[11];
    const float* b_hh    = (const float*)d_in[12];
    const float* W_log   = (const float*)d_in[13];
    const float* b_log   = (const float*)d_in[14];

    char* ws = (char*)d_ws;
    u16*   scat   = (u16*)(ws + O_SCAT);
    u16*   linh   = (u16*)(ws + O_LINH);
    u16*   Ph     = (u16*)(ws + O_R1);
    u16*   sc16   = (u16*)(ws + O_R1);    // reuses Ph region after gather
    u16*   attnh  = (u16*)(ws + O_ATTNH);
    u16*   erT    = (u16*)(ws + O_ERT);
    u16*   embh   = (u16*)(ws + O_EMBH);
    u16*   w2t    = (u16*)(ws + O_W2T);
    u16*   wlt    = (u16*)(ws + O_WLT);
    u16*   wst    = (u16*)(ws + O_WST);
    float* bl640  = (float*)(ws + O_BL);
    float* pad    = (float*)(ws + O_PAD);
    float* gates  = (float*)(ws + O_GATES);
    u16*   wiht   = (u16*)(ws + O_WIHT);
    u16*   wlogt  = (u16*)(ws + O_WLOGT);
    u16*   xcat   = (u16*)(ws + O_XCAT);
    u16*   hid16  = (u16*)(ws + O_HID16);
    float* glog   = (float*)(ws + O_GLOG);
    float* xmean  = (float*)(ws + O_XMEAN);

    float* out      = (float*)d_out;
    float* out_attn = out;
    float* out_hid  = out + BB * LL;
    float* out_cell = out + BB * LL + BB * HH;

    // ---- all staging conversions + tail-C bias inits + xmean init ----
    prep_k<<<dim3(20, 75, 12), 256, 0, stream>>>(
        emb, W_relu, W_lin, W_sig, W_ih, W_hh, W_log, b_lin, b_ih, b_hh, b_log,
        embh, w2t, wlt, wst, wiht, wlogt, bl640, gates, glog, xmean);

    // K1: Ph[2000][2400] = embh @ w2t^T  (Kp=640, B=weights -> BDIR)
    hgemm_v2<1, 1><<<dim3(19, 16, 1), 512, 0, stream>>>(
        embh, w2t, Ph, nullptr, nullptr, 0, nullptr,
        VV, H4, 640, 640, 640, H4, 0L, 0L, 0L);

    // K2: gather + relu -> scat er cols (+pads), pad flags
    gather_relu_k<<<dim3(BB * LL), 320, 0, stream>>>(records, Ph, b_relu, scat, pad);

    // K3: linh = f16(er @ W_lin + b_lin)  (Kp=640, N=640, B=weights -> BDIR)
    hgemm_v2<1, 1><<<dim3(5, 175, 1), 512, 0, stream>>>(
        scat, wlt, linh, bl640, nullptr, 0, nullptr,
        BB * LL, 640, 640, 1280, 640, 640, 0L, 0L, 0L);

    // K4: attnh[b] = f16(lin[b] @ er[b]^T)  (Kp=640, B=activations -> staged)
    hgemm_v2<1, 0><<<dim3(6, 6, BB), 512, 0, stream>>>(
        linh, scat, attnh, nullptr, nullptr, 0, nullptr,
        LL, LL, 640, 640, 1280, 704, (long)LL * 640, (long)LL * 1280, (long)LL * 704);

    // softmax: wave-per-row, in place on attnh (zeroes cols 700:704)
    softmax_w<<<dim3(175, BB), 256, 0, stream>>>(attnh, pad);

    // erT[b][h][l] = er f16, rows padded to 704
    transpz_k<u16><<<dim3(22, 19, BB), 256, 0, stream>>>(
        scat, erT, 700, 600, 1280, 704, 704, 600, (long)700 * 1280, (long)600 * 704);

    // K5: att = attnh[b] @ erT[b]^T -> scat cols 640:1240  (Kp=704, staged B)
    hgemm_v2<1, 0><<<dim3(5, 6, BB), 512, 0, stream>>>(
        attnh, erT, scat + 640, nullptr, nullptr, 0, nullptr,
        LL, HH, 704, 704, 704, 1280, (long)LL * 704, (long)HH * 704, (long)LL * 1280);

    // K6: sc16 = f16(sigmoid([er|att] @ wst^T + b_sig) * er)  (Kp=1280,
    //     B=weights -> BDIR) + fused xmean column-sums (reworked epilogue)
    hgemm_v2<2, 1><<<dim3(5, 175, 1), 512, 0, stream>>>(
        scat, wst, sc16, b_sig, scat, 1280, xmean,
        BB * LL, HH, 1280, 1280, 1280, 600, 0L, 0L, 0L);

    // tail: xcat (gather + xmean finalize), skinny split-K GEMMs
    xcat_k<<<dim3(4, BB), 256, 0, stream>>>(sc16, index, xmean, xcat);
    sgemm_k<<<dim3(38, 5), 256, 0, stream>>>(
        xcat, wiht, gates, H4, 256, 1280, 1280, H4);
    lstm_act_k<<<dim3(3, BB), 256, 0, stream>>>(gates, out_hid, out_cell, hid16);
    sgemm_k<<<dim3(11, 5), 256, 0, stream>>>(
        hid16, wlogt, glog, LL, 128, 640, 640, 704);
    logsoftmax_k<<<dim3(BB), 256, 0, stream>>>(glog, pad, index, out_attn);
}

// Round 7
// 410.882 us; speedup vs baseline: 1.2086x; 1.2086x over previous
//
#include <hip/hip_runtime.h>
#include <math.h>

typedef unsigned short u16;
typedef _Float16 half8 __attribute__((ext_vector_type(8)));
typedef float f32x4 __attribute__((ext_vector_type(4)));

#define BB 32
#define LL 700
#define HH 600
#define VV 2000
#define H4 2400

// ---- workspace byte offsets (16B aligned), K padded to 64-multiples ----
#define O_SCAT   0L            // f16 [22400][1280]: er 0:600(pad->640), att 640:1240(pad->1280)
#define O_LINH   57344000L     // f16 lin [22400][640]
#define O_R1     86016000L     // Ph f16 [2000][2400] -> sc16 f16 [22400][600]
#define O_ATTNH  112896000L    // f16 attn [32][700][704]
#define O_ERT    144435200L    // f16 erT [32][600][704]
#define O_EMBH   171468800L    // f16 emb [2000][640]
#define O_W2T    174028800L    // f16 W_relu^T [2400][640]
#define O_WLT    177100800L    // f16 W_lin^T [640][640]
#define O_WST    177920000L    // f16 W_sig^T [600][1280]
#define O_BL     179456000L    // fp32 b_lin padded [640]
#define O_PAD    179458560L    // fp32 [22400]
#define O_GATES  179624960L    // fp32 [32][2400]
#define O_WIHT   179932160L    // f16 [2400][1280]: W_ih^T | W_hh^T (k-padded halves)
#define O_WLOGT  186076160L    // f16 W_log^T [704][640]
#define O_XCAT   186977280L    // f16 [32][1280]: x | hid0 (k-padded halves)
#define O_HID16  187059200L    // f16 [32][640]
#define O_GLOG   187100160L    // fp32 [32][704]
#define O_XMEAN  187190272L    // fp32 [32][640] fused column-sum of sc (K6 epilogue)

__device__ inline u16 f2h(float x) { _Float16 h = (_Float16)x; u16 u; __builtin_memcpy(&u, &h, 2); return u; }
__device__ inline float h2f(u16 u) { _Float16 h; __builtin_memcpy(&h, &u, 2); return (float)h; }
__device__ inline float to_f(float x) { return x; }
__device__ inline float to_f(u16 x) { return h2f(x); }

// async global->LDS, 16B per lane, dest = wave-uniform base + lane*16
__device__ __forceinline__ void gll16(const u16* g, u16* l) {
    __builtin_amdgcn_global_load_lds(
        (__attribute__((address_space(1))) void*)g,
        (__attribute__((address_space(3))) void*)l, 16, 0, 0);
}

// ---------------------------------------------------------------------------
// R7 hgemm_v2: R2-exact staged core (128x128, BK=64, 8 waves, gll16 w16
// staging for BOTH A and B, double-buffered linear LDS 64KB -> 2 blk/CU,
// bank-swizzle pair, one __syncthreads per K-step) + R6's FIXED EPI=2
// epilogue (harness-verified in R6).
//
// GEMM config locked by 4 falsified alternatives:
//   R1: 256^2 4-phase     -> grid quantization, 2x makespan
//   R3: counted-vmcnt     -> == syncthreads (barrier drain not the stall)
//   R4: BK=32 @ 55% occ   -> worse (wave count not the stall)
//   R6: B direct-from-L2  -> 115us (exposes VMEM latency per K-step; the
//       staged path's value is its 1-K-step prefetch distance)
//
// EPI=2 epilogue (fixed): ONE int div per thread (bb0) + boundary compare;
// interior wave-halves combine 4 q-lane partials via __shfl_xor(16/32)
// (lanes share fr -> same n; wave-uniform branch) -> only q==0 atomics.
// EPI: 1 = f16 C (+bias), 2 = f16 sigmoid(acc+bias)*gate + xmean column-sums
// ---------------------------------------------------------------------------
template<int EPI>
__global__ __launch_bounds__(512, 4) void hgemm_v2(
    const u16* __restrict__ A, const u16* __restrict__ B,
    u16* __restrict__ C16, const float* __restrict__ bias,
    const u16* __restrict__ gate, int ldg,
    float* __restrict__ xmean,
    int M, int N, int Kp, int lda, int ldb, int ldc,
    long sAz, long sBz, long sCz)
{
    const int bz = blockIdx.z;
    A += sAz * bz;  B += sBz * bz;  C16 += sCz * bz;

    __shared__ __align__(16) u16 As[16384];   // [2][128][64]
    __shared__ __align__(16) u16 Bs[16384];

    const int tid = threadIdx.x;

    // ---- XCD-aware swizzle ----
    const int nx = gridDim.x, ny = gridDim.y;
    const int bid = blockIdx.y * nx + blockIdx.x;
    const int fg  = ny >> 3;
    const int gsz = nx << 3;
    int m_i, n_i;
    if (bid < fg * gsz) {
        int g = bid / gsz, r = bid - g * gsz;
        m_i = (g << 3) + (r & 7);
        n_i = r >> 3;
    } else {
        m_i = bid / nx;
        n_i = bid - m_i * nx;
    }
    const int m0 = m_i << 7, n0 = n_i << 7;

    const int wave = tid >> 6, lane = tid & 63;
    const int fr = lane & 15, q = lane >> 4;           // frag row / k-quarter
    const int s0 = (q ^ (fr & 7)) << 3;                // swizzled slot, half 0 (elems)
    const int wm = (wave >> 2) << 6;                   // 0 or 64
    const int wn = (wave & 3) << 5;                    // 0,32,64,96

    // ---- staging geometry ----
    const int srow = lane >> 3;                        // 0..7 within 8-row group
    const int kx   = ((lane & 7) ^ srow) << 3;         // pre-swizzled source chunk (elems)
    int ra0 = m0 + (wave << 4) + srow;       if (ra0 > M - 1) ra0 = M - 1;
    int ra1 = m0 + (wave << 4) + 8 + srow;   if (ra1 > M - 1) ra1 = M - 1;
    int rb0 = n0 + (wave << 4) + srow;       if (rb0 > N - 1) rb0 = N - 1;
    int rb1 = n0 + (wave << 4) + 8 + srow;   if (rb1 > N - 1) rb1 = N - 1;
    const u16* gA0 = A + (long)ra0 * lda + kx;
    const u16* gA1 = A + (long)ra1 * lda + kx;
    const u16* gB0 = B + (long)rb0 * ldb + kx;
    const u16* gB1 = B + (long)rb1 * ldb + kx;
    u16* sAw = (u16*)As + (wave << 10);                // wave slab segment (16 rows)
    u16* sBw = (u16*)Bs + (wave << 10);

    f32x4 acc[4][2];
    #pragma unroll
    for (int i = 0; i < 4; ++i)
        #pragma unroll
        for (int j = 0; j < 2; ++j) acc[i][j] = (f32x4)0.f;

    const int nk = Kp >> 6;

    // prologue: stage tile 0 (syncthreads drains vmcnt -> visible to all waves)
    gll16(gA0, sAw);  gll16(gA1, sAw + 512);
    gll16(gB0, sBw);  gll16(gB1, sBw + 512);
    __syncthreads();

    for (int t = 0; t < nk; ++t) {
        const int cur = (t & 1) << 13;                 // 0 / 8192 elems
        if (t + 1 < nk) {
            const int nxt = cur ^ 8192;
            const long ko = (long)(t + 1) << 6;
            gll16(gA0 + ko, sAw + nxt);  gll16(gA1 + ko, sAw + nxt + 512);
            gll16(gB0 + ko, sBw + nxt);  gll16(gB1 + ko, sBw + nxt + 512);
        }
        #pragma unroll
        for (int half = 0; half < 2; ++half) {
            const int sh = s0 ^ (half << 5);           // slot ^= 4 for k half 1
            half8 af[4], bf[2];
            #pragma unroll
            for (int i = 0; i < 4; ++i)
                af[i] = *(const half8*)&As[cur + ((wm + (i << 4) + fr) << 6) + sh];
            #pragma unroll
            for (int j = 0; j < 2; ++j)
                bf[j] = *(const half8*)&Bs[cur + ((wn + (j << 4) + fr) << 6) + sh];
            #pragma unroll
            for (int i = 0; i < 4; ++i)
                #pragma unroll
                for (int j = 0; j < 2; ++j)
                    acc[i][j] = __builtin_amdgcn_mfma_f32_16x16x32_f16(af[i], bf[j], acc[i][j], 0, 0, 0);
        }
        __syncthreads();
    }

    // epilogue: C/D layout col=lane&15, row=(lane>>4)*4+r
    const int lr = (lane >> 4) << 2;

    int  bb0 = 0, bound = 0;
    bool interior = false;
    if (EPI == 2) {
        const int mlo = m0 + wm, mhi = m0 + wm + 63;
        bb0   = mlo / 700;                 // ONE division per thread
        bound = (bb0 + 1) * 700;
        interior = (mhi < bound) && (mhi < M);
    }

    #pragma unroll
    for (int j = 0; j < 2; ++j) {
        int n = n0 + wn + (j << 4) + fr;
        if (n >= N) continue;
        float bv = bias ? bias[n] : 0.f;

        if (EPI == 2 && interior) {
            float ps = 0.f;
            #pragma unroll
            for (int i = 0; i < 4; ++i) {
                #pragma unroll
                for (int r = 0; r < 4; ++r) {
                    int m = m0 + wm + (i << 4) + lr + r;
                    float v = acc[i][j][r] + bv;
                    float sg = 1.f / (1.f + expf(-v));
                    float scv = sg * h2f(gate[(long)m * ldg + n]);
                    C16[(long)m * ldc + n] = f2h(scv);
                    ps += scv;
                }
            }
            // combine the 4 q-lanes (same fr -> same n, exec-uniform group)
            ps += __shfl_xor(ps, 16);
            ps += __shfl_xor(ps, 32);
            if (q == 0) atomicAdd(&xmean[bb0 * 640 + n], ps);
        } else {
            float ps = 0.f;
            int   cb = -1;
            #pragma unroll
            for (int i = 0; i < 4; ++i) {
                #pragma unroll
                for (int r = 0; r < 4; ++r) {
                    int m = m0 + wm + (i << 4) + lr + r;
                    if (m >= M) continue;
                    long off = (long)m * ldc + n;
                    float v = acc[i][j][r] + bv;
                    if (EPI == 1) C16[off] = f2h(v);
                    if (EPI == 2) {
                        float sg = 1.f / (1.f + expf(-v));
                        float scv = sg * h2f(gate[(long)m * ldg + n]);
                        C16[off] = f2h(scv);
                        int b = (m < bound) ? bb0 : bb0 + 1;   // tile spans <=2 batches
                        if (b != cb) {
                            if (cb >= 0) atomicAdd(&xmean[cb * 640 + n], ps);
                            cb = b;  ps = 0.f;
                        }
                        ps += scv;
                    }
                }
            }
            if (EPI == 2 && cb >= 0) atomicAdd(&xmean[cb * 640 + n], ps);
        }
    }
}

// ---------------------------------------------------------------------------
// Skinny split-K GEMM for M=32 tails.
// ---------------------------------------------------------------------------
__global__ __launch_bounds__(256) void sgemm_k(
    const u16* __restrict__ A, const u16* __restrict__ B, float* __restrict__ C,
    int N, int Kseg, int lda, int ldb, int ldc)
{
    const int wave = threadIdx.x >> 6, lane = threadIdx.x & 63;
    const int fr = lane & 15, q8 = (lane >> 4) << 3;
    int n = blockIdx.x * 64 + wave * 16 + fr;
    int nc = (n < N) ? n : N - 1;
    const int k0 = blockIdx.y * Kseg;
    const u16* pa0 = A + (long)fr * lda + q8;          // m = fr
    const u16* pa1 = A + (long)(fr + 16) * lda + q8;   // m = fr+16
    const u16* pb  = B + (long)nc * ldb + q8;
    f32x4 acc0 = (f32x4)0.f, acc1 = (f32x4)0.f;
    #pragma unroll 2
    for (int k = k0; k < k0 + Kseg; k += 32) {
        half8 a0 = *(const half8*)(pa0 + k);
        half8 a1 = *(const half8*)(pa1 + k);
        half8 bv = *(const half8*)(pb + k);
        acc0 = __builtin_amdgcn_mfma_f32_16x16x32_f16(a0, bv, acc0, 0, 0, 0);
        acc1 = __builtin_amdgcn_mfma_f32_16x16x32_f16(a1, bv, acc1, 0, 0, 0);
    }
    if (n >= N) return;
    const int mr = (lane >> 4) << 2;       // row = (lane>>4)*4 + r
    #pragma unroll
    for (int r = 0; r < 4; ++r) {
        atomicAdd(&C[(long)(mr + r) * ldc + n], acc0[r]);
        atomicAdd(&C[(long)(mr + r + 16) * ldc + n], acc1[r]);
    }
}

// ---------------------------------------------------------------------------
// Fused prep kernel: all weight transposes + emb cast + bias pads + tail-C
// bias-inits + xmean zero-init in ONE launch. Grid (20,75,12).
// ---------------------------------------------------------------------------
__global__ __launch_bounds__(256) void prep_k(
    const float* __restrict__ emb, const float* __restrict__ W_relu,
    const float* __restrict__ W_lin, const float* __restrict__ W_sig,
    const float* __restrict__ W_ih, const float* __restrict__ W_hh,
    const float* __restrict__ W_log, const float* __restrict__ b_lin,
    const float* __restrict__ b_ih, const float* __restrict__ b_hh,
    const float* __restrict__ b_log,
    u16* __restrict__ embh, u16* __restrict__ w2t, u16* __restrict__ wlt,
    u16* __restrict__ wst, u16* __restrict__ wiht, u16* __restrict__ wlogt,
    float* __restrict__ bl640, float* __restrict__ gates, float* __restrict__ glog,
    float* __restrict__ xmean)
{
    __shared__ float t[32][33];
    const int z = blockIdx.z, bx = blockIdx.x, by = blockIdx.y;
    const int tid = threadIdx.x;

    if (z == 10) {
        int r = by * 32 + (tid >> 5), c = bx * 32 + (tid & 31);
        #pragma unroll
        for (int dy = 0; dy < 32; dy += 8) {
            int rr = r + dy;
            if (rr < VV && c < 640)
                embh[(long)rr * 640 + c] = (c < 600) ? f2h(emb[(long)rr * 600 + c]) : 0;
        }
        return;
    }
    if (z == 11) {
        long idx = ((long)bx * 75 + by) * 256 + tid;
        const long NG = 640 + (long)BB * H4;
        const long NL = NG + (long)BB * 704;
        const long NX = NL + (long)BB * 640;
        if (idx < 640) {
            bl640[idx] = (idx < 600) ? b_lin[idx] : 0.f;
        } else if (idx < NG) {
            long i = idx - 640;
            int n = (int)(i % H4);
            gates[i] = b_ih[n] + b_hh[n];
        } else if (idx < NL) {
            long i = idx - NG;
            int l = (int)(i % 704);
            glog[i] = (l < 700) ? b_log[l] : 0.f;
        } else if (idx < NX) {
            xmean[idx - NL] = 0.f;
        }
        return;
    }

    const float* s; u16* d;
    int R, C, lds_, ldo, Rpad, Cpad;
    if (z < 4)      { s = W_relu + 360000L * z; d = w2t + 384000L * z;
                      R = 600; C = 600; lds_ = 600; ldo = 640;  Rpad = 640; Cpad = 600; }
    else if (z == 4){ s = W_lin;           d = wlt;
                      R = 600; C = 600; lds_ = 600; ldo = 640;  Rpad = 640; Cpad = 640; }
    else if (z == 5){ s = W_sig;           d = wst;
                      R = 600; C = 600; lds_ = 600; ldo = 1280; Rpad = 640; Cpad = 600; }
    else if (z == 6){ s = W_sig + 360000;  d = wst + 640;
                      R = 600; C = 600; lds_ = 600; ldo = 1280; Rpad = 640; Cpad = 600; }
    else if (z == 7){ s = W_ih;            d = wiht;
                      R = 600; C = H4;  lds_ = H4;  ldo = 1280; Rpad = 640; Cpad = H4; }
    else if (z == 8){ s = W_hh;            d = wiht + 640;
                      R = 600; C = H4;  lds_ = H4;  ldo = 1280; Rpad = 640; Cpad = H4; }
    else            { s = W_log;           d = wlogt;
                      R = 600; C = 700; lds_ = 700; ldo = 640;  Rpad = 640; Cpad = 704; }

    int r0 = bx * 32, c0 = by * 32;
    if (r0 >= Rpad || c0 >= Cpad) return;
    int tx = tid & 31, ty = tid >> 5;
    #pragma unroll
    for (int dy = 0; dy < 32; dy += 8) {
        int r = r0 + ty + dy, c = c0 + tx;
        t[ty + dy][tx] = (r < R && c < C) ? s[(long)r * lds_ + c] : 0.f;
    }
    __syncthreads();
    #pragma unroll
    for (int dy = 0; dy < 32; dy += 8) {
        int c = c0 + ty + dy, r = r0 + tx;
        if (r < Rpad && c < Cpad) d[(long)c * ldo + r] = f2h(t[tx][ty + dy]);
    }
}

// ---------------------------------------------------------------------------
// transpose+cast (u16 source): kept for erT only.
// ---------------------------------------------------------------------------
template<typename T>
__global__ __launch_bounds__(256) void transpz_k(
    const T* __restrict__ s, u16* __restrict__ d,
    int R, int C, int lds_, int ldo, int Rpad, int Cpad, long zs_s, long zs_d)
{
    __shared__ float t[32][33];
    s += zs_s * blockIdx.z;  d += zs_d * blockIdx.z;
    int r0 = blockIdx.x * 32, c0 = blockIdx.y * 32;
    int tx = threadIdx.x & 31, ty = threadIdx.x >> 5;
    #pragma unroll
    for (int dy = 0; dy < 32; dy += 8) {
        int r = r0 + ty + dy, c = c0 + tx;
        t[ty + dy][tx] = (r < R && c < C) ? to_f(s[(long)r * lds_ + c]) : 0.f;
    }
    __syncthreads();
    #pragma unroll
    for (int dy = 0; dy < 32; dy += 8) {
        int c = c0 + ty + dy, r = r0 + tx;
        if (r < Rpad && c < Cpad) d[(long)c * ldo + r] = f2h(t[tx][ty + dy]);
    }
}

// er (2 h per thread, uint loads) into scat cols 0:600 + zero pads; pad flag
__global__ __launch_bounds__(320) void gather_relu_k(
    const int* __restrict__ rec, const u16* __restrict__ Ph,
    const float* __restrict__ b_relu, u16* __restrict__ scat, float* __restrict__ pad)
{
    int row = blockIdx.x;
    int t = threadIdx.x;
    int r0 = rec[row * 4 + 0], r1 = rec[row * 4 + 1];
    int r2 = rec[row * 4 + 2], r3 = rec[row * 4 + 3];
    u16* srow = scat + (long)row * 1280;
    if (t < 300) {
        int h = t << 1;
        uint a0 = *(const uint*)&Ph[(long)r0 * H4 + h];
        uint a1 = *(const uint*)&Ph[(long)r1 * H4 + 600 + h];
        uint a2 = *(const uint*)&Ph[(long)r2 * H4 + 1200 + h];
        uint a3 = *(const uint*)&Ph[(long)r3 * H4 + 1800 + h];
        float lo = b_relu[h]     + h2f((u16)a0) + h2f((u16)a1) + h2f((u16)a2) + h2f((u16)a3);
        float hi = b_relu[h + 1] + h2f((u16)(a0 >> 16)) + h2f((u16)(a1 >> 16))
                                 + h2f((u16)(a2 >> 16)) + h2f((u16)(a3 >> 16));
        uint o = (uint)f2h(fmaxf(lo, 0.f)) | ((uint)f2h(fmaxf(hi, 0.f)) << 16);
        *(uint*)&srow[h] = o;
    } else {
        int i = t - 300;
        *(uint*)&srow[600 + (i << 1)]  = 0;
        *(uint*)&srow[1240 + (i << 1)] = 0;
    }
    if (t == 0) {
        int mx = max(max(r0, r1), max(r2, r3));
        pad[row] = (mx == 0) ? 1.f : 0.f;
    }
}

// ---------------------------------------------------------------------------
// masked softmax, wave-per-row
// ---------------------------------------------------------------------------
__global__ __launch_bounds__(256) void softmax_w(u16* __restrict__ attnh,
                                                 const float* __restrict__ pad)
{
    const int wave = threadIdx.x >> 6, lane = threadIdx.x & 63;
    const int l = blockIdx.x * 4 + wave, b = blockIdx.y;
    u16* row = attnh + (long)b * (LL * 704) + (long)l * 704;
    const float* pb = pad + b * LL;
    const bool rowpad = pb[l] != 0.f;

    float v[12];
    float mx = -INFINITY;
    #pragma unroll
    for (int i = 0; i < 6; ++i) {
        int e0 = (lane + (i << 6)) << 1;
        float x0 = -INFINITY, x1 = -INFINITY;
        if (e0 < 704) {
            uint u = *(const uint*)&row[e0];
            if (e0 < LL && !(rowpad || e0 == l || pb[e0] != 0.f)) x0 = h2f((u16)u);
            int e1 = e0 + 1;
            if (e1 < LL && !(rowpad || e1 == l || pb[e1] != 0.f)) x1 = h2f((u16)(u >> 16));
        }
        v[2 * i] = x0;  v[2 * i + 1] = x1;
        mx = fmaxf(mx, fmaxf(x0, x1));
    }
    #pragma unroll
    for (int m = 32; m > 0; m >>= 1) mx = fmaxf(mx, __shfl_xor(mx, m));
    mx = fmaxf(mx, -1e30f);

    float sum = 0.f;
    #pragma unroll
    for (int i = 0; i < 12; ++i) { v[i] = expf(v[i] - mx); sum += v[i]; }
    #pragma unroll
    for (int m = 32; m > 0; m >>= 1) sum += __shfl_xor(sum, m);
    float inv = (sum > 0.f) ? 1.f / sum : 0.f;

    #pragma unroll
    for (int i = 0; i < 6; ++i) {
        int e0 = (lane + (i << 6)) << 1;
        if (e0 < 704) {
            uint u = (uint)f2h(v[2 * i] * inv) | ((uint)f2h(v[2 * i + 1] * inv) << 16);
            *(uint*)&row[e0] = u;
        }
    }
}

// fused xcat: x-gather (bx==3) + xmean finalize (bx<3) -> f16 xcat halves
__global__ __launch_bounds__(256) void xcat_k(const u16* __restrict__ sc,
                                              const int* __restrict__ index,
                                              const float* __restrict__ xmean,
                                              u16* __restrict__ xcat)
{
    int b = blockIdx.y;
    if (blockIdx.x == 3) {
        const u16* src = sc + ((long)b * LL + index[b]) * HH;
        u16* dst = xcat + b * 1280;
        for (int j = threadIdx.x; j < 1280; j += 256) {
            if (j < 600) dst[j] = src[j];
            else if (j < 640) dst[j] = 0;
            else if (j >= 1240) dst[j] = 0;
        }
        return;
    }
    int h = blockIdx.x * 256 + threadIdx.x;
    if (h >= HH) return;
    xcat[b * 1280 + 640 + h] = f2h(xmean[b * 640 + h] * (1.f / 700.f));
}

// cell = sigmoid(i)*tanh(g); hidden = sigmoid(o)*tanh(cell); + f16 hidden copy
__global__ void lstm_act_k(const float* __restrict__ gates,
                           float* __restrict__ out_hid, float* __restrict__ out_cell,
                           u16* __restrict__ hid16)
{
    int h = blockIdx.x * 256 + threadIdx.x;
    int b = blockIdx.y;
    if (h >= 640) return;
    if (h >= HH) { hid16[b * 640 + h] = 0; return; }
    const float* g = gates + b * H4;
    float gi = g[h], gg = g[1200 + h], go = g[1800 + h];
    float c = (1.f / (1.f + expf(-gi))) * tanhf(gg);
    float hd = (1.f / (1.f + expf(-go))) * tanhf(c);
    out_hid[b * HH + h] = hd;
    out_cell[b * HH + h] = c;
    hid16[b * 640 + h] = f2h(hd);
}

// masked log-softmax of glog row -> out
__global__ __launch_bounds__(256) void logsoftmax_k(const float* __restrict__ glog,
                                                    const float* __restrict__ pad,
                                                    const int* __restrict__ index,
                                                    float* __restrict__ out)
{
    int b = blockIdx.x;
    int t = threadIdx.x;
    int idx = index[b];
    __shared__ float red[256];
    float v[3];
    float mx = -INFINITY;
    #pragma unroll
    for (int ii = 0; ii < 3; ++ii) {
        int l = ii * 256 + t;
        float x = -INFINITY;
        if (l < LL && !(pad[b * LL + l] != 0.f || l == idx)) x = glog[b * 704 + l];
        v[ii] = x;
        mx = fmaxf(mx, x);
    }
    red[t] = mx; __syncthreads();
    for (int s = 128; s > 0; s >>= 1) {
        if (t < s) red[t] = fmaxf(red[t], red[t + s]);
        __syncthreads();
    }
    mx = red[0]; __syncthreads();
    float sum = 0.f;
    #pragma unroll
    for (int ii = 0; ii < 3; ++ii) {
        int l = ii * 256 + t;
        if (l < LL) sum += expf(v[ii] - mx);
    }
    red[t] = sum; __syncthreads();
    for (int s = 128; s > 0; s >>= 1) {
        if (t < s) red[t] += red[t + s];
        __syncthreads();
    }
    float lse = mx + logf(red[0]);
    #pragma unroll
    for (int ii = 0; ii < 3; ++ii) {
        int l = ii * 256 + t;
        if (l < LL) out[b * LL + l] = fmaxf(v[ii] - lse, -1e30f);
    }
}

// ---------------------------------------------------------------------------
extern "C" void kernel_launch(void* const* d_in, const int* in_sizes, int n_in,
                              void* d_out, int out_size, void* d_ws, size_t ws_size,
                              hipStream_t stream)
{
    const int*   records = (const int*)d_in[0];
    const int*   index   = (const int*)d_in[1];
    const float* emb     = (const float*)d_in[2];
    const float* W_relu  = (const float*)d_in[3];
    const float* b_relu  = (const float*)d_in[4];
    const float* W_lin   = (const float*)d_in[5];
    const float* b_lin   = (const float*)d_in[6];
    const float* W_sig   = (const float*)d_in[7];
    const float* b_sig   = (const float*)d_in[8];
    const float* W_ih    = (const float*)d_in[9];
    const float* W_hh    = (const float*)d_in[10];
    const float* b_ih    = (const float*)d_in[11];
    const float* b_hh    = (const float*)d_in[12];
    const float* W_log   = (const float*)d_in[13];
    const float* b_log   = (const float*)d_in[14];

    char* ws = (char*)d_ws;
    u16*   scat   = (u16*)(ws + O_SCAT);
    u16*   linh   = (u16*)(ws + O_LINH);
    u16*   Ph     = (u16*)(ws + O_R1);
    u16*   sc16   = (u16*)(ws + O_R1);    // reuses Ph region after gather
    u16*   attnh  = (u16*)(ws + O_ATTNH);
    u16*   erT    = (u16*)(ws + O_ERT);
    u16*   embh   = (u16*)(ws + O_EMBH);
    u16*   w2t    = (u16*)(ws + O_W2T);
    u16*   wlt    = (u16*)(ws + O_WLT);
    u16*   wst    = (u16*)(ws + O_WST);
    float* bl640  = (float*)(ws + O_BL);
    float* pad    = (float*)(ws + O_PAD);
    float* gates  = (float*)(ws + O_GATES);
    u16*   wiht   = (u16*)(ws + O_WIHT);
    u16*   wlogt  = (u16*)(ws + O_WLOGT);
    u16*   xcat   = (u16*)(ws + O_XCAT);
    u16*   hid16  = (u16*)(ws + O_HID16);
    float* glog   = (float*)(ws + O_GLOG);
    float* xmean  = (float*)(ws + O_XMEAN);

    float* out      = (float*)d_out;
    float* out_attn = out;
    float* out_hid  = out + BB * LL;
    float* out_cell = out + BB * LL + BB * HH;

    // ---- all staging conversions + tail-C bias inits + xmean init ----
    prep_k<<<dim3(20, 75, 12), 256, 0, stream>>>(
        emb, W_relu, W_lin, W_sig, W_ih, W_hh, W_log, b_lin, b_ih, b_hh, b_log,
        embh, w2t, wlt, wst, wiht, wlogt, bl640, gates, glog, xmean);

    // K1: Ph[2000][2400] = embh @ w2t^T  (Kp=640)
    hgemm_v2<1><<<dim3(19, 16, 1), 512, 0, stream>>>(
        embh, w2t, Ph, nullptr, nullptr, 0, nullptr,
        VV, H4, 640, 640, 640, H4, 0L, 0L, 0L);

    // K2: gather + relu -> scat er cols (+pads), pad flags
    gather_relu_k<<<dim3(BB * LL), 320, 0, stream>>>(records, Ph, b_relu, scat, pad);

    // K3: linh = f16(er @ W_lin + b_lin)  (Kp=640, N=640)
    hgemm_v2<1><<<dim3(5, 175, 1), 512, 0, stream>>>(
        scat, wlt, linh, bl640, nullptr, 0, nullptr,
        BB * LL, 640, 640, 1280, 640, 640, 0L, 0L, 0L);

    // K4: attnh[b] = f16(lin[b] @ er[b]^T)  (Kp=640, stride-704 out)
    hgemm_v2<1><<<dim3(6, 6, BB), 512, 0, stream>>>(
        linh, scat, attnh, nullptr, nullptr, 0, nullptr,
        LL, LL, 640, 640, 1280, 704, (long)LL * 640, (long)LL * 1280, (long)LL * 704);

    // softmax: wave-per-row, in place on attnh (zeroes cols 700:704)
    softmax_w<<<dim3(175, BB), 256, 0, stream>>>(attnh, pad);

    // erT[b][h][l] = er f16, rows padded to 704
    transpz_k<u16><<<dim3(22, 19, BB), 256, 0, stream>>>(
        scat, erT, 700, 600, 1280, 704, 704, 600, (long)700 * 1280, (long)600 * 704);

    // K5: att = attnh[b] @ erT[b]^T -> scat cols 640:1240  (Kp=704)
    hgemm_v2<1><<<dim3(5, 6, BB), 512, 0, stream>>>(
        attnh, erT, scat + 640, nullptr, nullptr, 0, nullptr,
        LL, HH, 704, 704, 704, 1280, (long)LL * 704, (long)HH * 704, (long)LL * 1280);

    // K6: sc16 = f16(sigmoid([er|att] @ wst^T + b_sig) * er)  (Kp=1280)
    //     + fused xmean column-sums (fixed epilogue)
    hgemm_v2<2><<<dim3(5, 175, 1), 512, 0, stream>>>(
        scat, wst, sc16, b_sig, scat, 1280, xmean,
        BB * LL, HH, 1280, 1280, 1280, 600, 0L, 0L, 0L);

    // tail: xcat (gather + xmean finalize), skinny split-K GEMMs
    xcat_k<<<dim3(4, BB), 256, 0, stream>>>(sc16, index, xmean, xcat);
    sgemm_k<<<dim3(38, 5), 256, 0, stream>>>(
        xcat, wiht, gates, H4, 256, 1280, 1280, H4);
    lstm_act_k<<<dim3(3, BB), 256, 0, stream>>>(gates, out_hid, out_cell, hid16);
    sgemm_k<<<dim3(11, 5), 256, 0, stream>>>(
        hid16, wlogt, glog, LL, 128, 640, 640, 704);
    logsoftmax_k<<<dim3(BB), 256, 0, stream>>>(glog, pad, index, out_attn);
}

// Round 8
// 405.299 us; speedup vs baseline: 1.2252x; 1.0138x over previous
//
#include <hip/hip_runtime.h>
#include <math.h>

typedef unsigned short u16;
typedef _Float16 half8 __attribute__((ext_vector_type(8)));
typedef float f32x4 __attribute__((ext_vector_type(4)));

#define BB 32
#define LL 700
#define HH 600
#define VV 2000
#define H4 2400

// ---- workspace byte offsets (16B aligned), K padded to 64-multiples ----
#define O_SCAT   0L            // f16 [22400][1280]: er 0:600(pad->640), att 640:1240(pad->1280)
#define O_LINH   57344000L     // f16 lin [22400][640]
#define O_R1     86016000L     // Ph f16 [2000][2400] -> sc16 f16 [22400][600]
#define O_ATTNH  112896000L    // f16 attn [32][700][704]
#define O_ERT    144435200L    // f16 erT [32][600][704]
#define O_EMBH   171468800L    // f16 emb [2000][640]
#define O_W2T    174028800L    // f16 W_relu^T [2400][640]
#define O_WLT    177100800L    // f16 W_lin^T [640][640]
#define O_WST    177920000L    // f16 W_sig^T [600][1280]
#define O_BL     179456000L    // fp32 b_lin padded [640]
#define O_PAD    179458560L    // fp32 [22400]
#define O_GATES  179624960L    // fp32 [32][2400]
#define O_WIHT   179932160L    // f16 [2400][1280]: W_ih^T | W_hh^T (k-padded halves)
#define O_WLOGT  186076160L    // f16 W_log^T [704][640]
#define O_XCAT   186977280L    // f16 [32][1280]: x | hid0 (k-padded halves)
#define O_HID16  187059200L    // f16 [32][640]
#define O_GLOG   187100160L    // fp32 [32][704]
#define O_XMEAN  187190272L    // fp32 [32][640] fused column-sum of sc (K6 epilogue)

__device__ inline u16 f2h(float x) { _Float16 h = (_Float16)x; u16 u; __builtin_memcpy(&u, &h, 2); return u; }
__device__ inline float h2f(u16 u) { _Float16 h; __builtin_memcpy(&h, &u, 2); return (float)h; }

// async global->LDS, 16B per lane, dest = wave-uniform base + lane*16
__device__ __forceinline__ void gll16(const u16* g, u16* l) {
    __builtin_amdgcn_global_load_lds(
        (__attribute__((address_space(1))) void*)g,
        (__attribute__((address_space(3))) void*)l, 16, 0, 0);
}

// ---------------------------------------------------------------------------
// hgemm_v2 (locked): R2 staged core (128x128, BK=64, 8 waves, gll16 w16
// staging for BOTH A and B, double-buffered linear LDS 64KB -> 2 blk/CU,
// bank-swizzle pair, one __syncthreads per K-step) + fixed EPI=2 epilogue.
//
// GEMM config locked by 4 falsified alternatives:
//   R1: 256^2 4-phase     -> grid quantization, 2x makespan
//   R3: counted-vmcnt     -> == syncthreads (barrier drain not the stall)
//   R4: BK=32 @ 55% occ   -> worse (wave count not the stall)
//   R6: B direct-from-L2  -> 115us (staged path's value = 1-K-step prefetch)
//
// EPI: 1 = f16 C (+bias), 2 = f16 sigmoid(acc+bias)*gate + xmean column-sums
// ---------------------------------------------------------------------------
template<int EPI>
__global__ __launch_bounds__(512, 4) void hgemm_v2(
    const u16* __restrict__ A, const u16* __restrict__ B,
    u16* __restrict__ C16, const float* __restrict__ bias,
    const u16* __restrict__ gate, int ldg,
    float* __restrict__ xmean,
    int M, int N, int Kp, int lda, int ldb, int ldc,
    long sAz, long sBz, long sCz)
{
    const int bz = blockIdx.z;
    A += sAz * bz;  B += sBz * bz;  C16 += sCz * bz;

    __shared__ __align__(16) u16 As[16384];   // [2][128][64]
    __shared__ __align__(16) u16 Bs[16384];

    const int tid = threadIdx.x;

    // ---- XCD-aware swizzle ----
    const int nx = gridDim.x, ny = gridDim.y;
    const int bid = blockIdx.y * nx + blockIdx.x;
    const int fg  = ny >> 3;
    const int gsz = nx << 3;
    int m_i, n_i;
    if (bid < fg * gsz) {
        int g = bid / gsz, r = bid - g * gsz;
        m_i = (g << 3) + (r & 7);
        n_i = r >> 3;
    } else {
        m_i = bid / nx;
        n_i = bid - m_i * nx;
    }
    const int m0 = m_i << 7, n0 = n_i << 7;

    const int wave = tid >> 6, lane = tid & 63;
    const int fr = lane & 15, q = lane >> 4;           // frag row / k-quarter
    const int s0 = (q ^ (fr & 7)) << 3;                // swizzled slot, half 0 (elems)
    const int wm = (wave >> 2) << 6;                   // 0 or 64
    const int wn = (wave & 3) << 5;                    // 0,32,64,96

    // ---- staging geometry ----
    const int srow = lane >> 3;                        // 0..7 within 8-row group
    const int kx   = ((lane & 7) ^ srow) << 3;         // pre-swizzled source chunk (elems)
    int ra0 = m0 + (wave << 4) + srow;       if (ra0 > M - 1) ra0 = M - 1;
    int ra1 = m0 + (wave << 4) + 8 + srow;   if (ra1 > M - 1) ra1 = M - 1;
    int rb0 = n0 + (wave << 4) + srow;       if (rb0 > N - 1) rb0 = N - 1;
    int rb1 = n0 + (wave << 4) + 8 + srow;   if (rb1 > N - 1) rb1 = N - 1;
    const u16* gA0 = A + (long)ra0 * lda + kx;
    const u16* gA1 = A + (long)ra1 * lda + kx;
    const u16* gB0 = B + (long)rb0 * ldb + kx;
    const u16* gB1 = B + (long)rb1 * ldb + kx;
    u16* sAw = (u16*)As + (wave << 10);                // wave slab segment (16 rows)
    u16* sBw = (u16*)Bs + (wave << 10);

    f32x4 acc[4][2];
    #pragma unroll
    for (int i = 0; i < 4; ++i)
        #pragma unroll
        for (int j = 0; j < 2; ++j) acc[i][j] = (f32x4)0.f;

    const int nk = Kp >> 6;

    // prologue: stage tile 0 (syncthreads drains vmcnt -> visible to all waves)
    gll16(gA0, sAw);  gll16(gA1, sAw + 512);
    gll16(gB0, sBw);  gll16(gB1, sBw + 512);
    __syncthreads();

    for (int t = 0; t < nk; ++t) {
        const int cur = (t & 1) << 13;                 // 0 / 8192 elems
        if (t + 1 < nk) {
            const int nxt = cur ^ 8192;
            const long ko = (long)(t + 1) << 6;
            gll16(gA0 + ko, sAw + nxt);  gll16(gA1 + ko, sAw + nxt + 512);
            gll16(gB0 + ko, sBw + nxt);  gll16(gB1 + ko, sBw + nxt + 512);
        }
        #pragma unroll
        for (int half = 0; half < 2; ++half) {
            const int sh = s0 ^ (half << 5);           // slot ^= 4 for k half 1
            half8 af[4], bf[2];
            #pragma unroll
            for (int i = 0; i < 4; ++i)
                af[i] = *(const half8*)&As[cur + ((wm + (i << 4) + fr) << 6) + sh];
            #pragma unroll
            for (int j = 0; j < 2; ++j)
                bf[j] = *(const half8*)&Bs[cur + ((wn + (j << 4) + fr) << 6) + sh];
            #pragma unroll
            for (int i = 0; i < 4; ++i)
                #pragma unroll
                for (int j = 0; j < 2; ++j)
                    acc[i][j] = __builtin_amdgcn_mfma_f32_16x16x32_f16(af[i], bf[j], acc[i][j], 0, 0, 0);
        }
        __syncthreads();
    }

    // epilogue: C/D layout col=lane&15, row=(lane>>4)*4+r
    const int lr = (lane >> 4) << 2;

    int  bb0 = 0, bound = 0;
    bool interior = false;
    if (EPI == 2) {
        const int mlo = m0 + wm, mhi = m0 + wm + 63;
        bb0   = mlo / 700;                 // ONE division per thread
        bound = (bb0 + 1) * 700;
        interior = (mhi < bound) && (mhi < M);
    }

    #pragma unroll
    for (int j = 0; j < 2; ++j) {
        int n = n0 + wn + (j << 4) + fr;
        if (n >= N) continue;
        float bv = bias ? bias[n] : 0.f;

        if (EPI == 2 && interior) {
            float ps = 0.f;
            #pragma unroll
            for (int i = 0; i < 4; ++i) {
                #pragma unroll
                for (int r = 0; r < 4; ++r) {
                    int m = m0 + wm + (i << 4) + lr + r;
                    float v = acc[i][j][r] + bv;
                    float sg = 1.f / (1.f + expf(-v));
                    float scv = sg * h2f(gate[(long)m * ldg + n]);
                    C16[(long)m * ldc + n] = f2h(scv);
                    ps += scv;
                }
            }
            // combine the 4 q-lanes (same fr -> same n, exec-uniform group)
            ps += __shfl_xor(ps, 16);
            ps += __shfl_xor(ps, 32);
            if (q == 0) atomicAdd(&xmean[bb0 * 640 + n], ps);
        } else {
            float ps = 0.f;
            int   cb = -1;
            #pragma unroll
            for (int i = 0; i < 4; ++i) {
                #pragma unroll
                for (int r = 0; r < 4; ++r) {
                    int m = m0 + wm + (i << 4) + lr + r;
                    if (m >= M) continue;
                    long off = (long)m * ldc + n;
                    float v = acc[i][j][r] + bv;
                    if (EPI == 1) C16[off] = f2h(v);
                    if (EPI == 2) {
                        float sg = 1.f / (1.f + expf(-v));
                        float scv = sg * h2f(gate[(long)m * ldg + n]);
                        C16[off] = f2h(scv);
                        int b = (m < bound) ? bb0 : bb0 + 1;   // tile spans <=2 batches
                        if (b != cb) {
                            if (cb >= 0) atomicAdd(&xmean[cb * 640 + n], ps);
                            cb = b;  ps = 0.f;
                        }
                        ps += scv;
                    }
                }
            }
            if (EPI == 2 && cb >= 0) atomicAdd(&xmean[cb * 640 + n], ps);
        }
    }
}

// ---------------------------------------------------------------------------
// Skinny split-K GEMM for M=32 tails.
// ---------------------------------------------------------------------------
__global__ __launch_bounds__(256) void sgemm_k(
    const u16* __restrict__ A, const u16* __restrict__ B, float* __restrict__ C,
    int N, int Kseg, int lda, int ldb, int ldc)
{
    const int wave = threadIdx.x >> 6, lane = threadIdx.x & 63;
    const int fr = lane & 15, q8 = (lane >> 4) << 3;
    int n = blockIdx.x * 64 + wave * 16 + fr;
    int nc = (n < N) ? n : N - 1;
    const int k0 = blockIdx.y * Kseg;
    const u16* pa0 = A + (long)fr * lda + q8;          // m = fr
    const u16* pa1 = A + (long)(fr + 16) * lda + q8;   // m = fr+16
    const u16* pb  = B + (long)nc * ldb + q8;
    f32x4 acc0 = (f32x4)0.f, acc1 = (f32x4)0.f;
    #pragma unroll 2
    for (int k = k0; k < k0 + Kseg; k += 32) {
        half8 a0 = *(const half8*)(pa0 + k);
        half8 a1 = *(const half8*)(pa1 + k);
        half8 bv = *(const half8*)(pb + k);
        acc0 = __builtin_amdgcn_mfma_f32_16x16x32_f16(a0, bv, acc0, 0, 0, 0);
        acc1 = __builtin_amdgcn_mfma_f32_16x16x32_f16(a1, bv, acc1, 0, 0, 0);
    }
    if (n >= N) return;
    const int mr = (lane >> 4) << 2;       // row = (lane>>4)*4 + r
    #pragma unroll
    for (int r = 0; r < 4; ++r) {
        atomicAdd(&C[(long)(mr + r) * ldc + n], acc0[r]);
        atomicAdd(&C[(long)(mr + r + 16) * ldc + n], acc1[r]);
    }
}

// ---------------------------------------------------------------------------
// Fused prep kernel: all weight transposes + emb cast + bias pads + tail-C
// bias-inits + xmean zero-init in ONE launch. Grid (20,75,12).
// ---------------------------------------------------------------------------
__global__ __launch_bounds__(256) void prep_k(
    const float* __restrict__ emb, const float* __restrict__ W_relu,
    const float* __restrict__ W_lin, const float* __restrict__ W_sig,
    const float* __restrict__ W_ih, const float* __restrict__ W_hh,
    const float* __restrict__ W_log, const float* __restrict__ b_lin,
    const float* __restrict__ b_ih, const float* __restrict__ b_hh,
    const float* __restrict__ b_log,
    u16* __restrict__ embh, u16* __restrict__ w2t, u16* __restrict__ wlt,
    u16* __restrict__ wst, u16* __restrict__ wiht, u16* __restrict__ wlogt,
    float* __restrict__ bl640, float* __restrict__ gates, float* __restrict__ glog,
    float* __restrict__ xmean)
{
    __shared__ float t[32][33];
    const int z = blockIdx.z, bx = blockIdx.x, by = blockIdx.y;
    const int tid = threadIdx.x;

    if (z == 10) {
        int r = by * 32 + (tid >> 5), c = bx * 32 + (tid & 31);
        #pragma unroll
        for (int dy = 0; dy < 32; dy += 8) {
            int rr = r + dy;
            if (rr < VV && c < 640)
                embh[(long)rr * 640 + c] = (c < 600) ? f2h(emb[(long)rr * 600 + c]) : 0;
        }
        return;
    }
    if (z == 11) {
        long idx = ((long)bx * 75 + by) * 256 + tid;
        const long NG = 640 + (long)BB * H4;
        const long NL = NG + (long)BB * 704;
        const long NX = NL + (long)BB * 640;
        if (idx < 640) {
            bl640[idx] = (idx < 600) ? b_lin[idx] : 0.f;
        } else if (idx < NG) {
            long i = idx - 640;
            int n = (int)(i % H4);
            gates[i] = b_ih[n] + b_hh[n];
        } else if (idx < NL) {
            long i = idx - NG;
            int l = (int)(i % 704);
            glog[i] = (l < 700) ? b_log[l] : 0.f;
        } else if (idx < NX) {
            xmean[idx - NL] = 0.f;
        }
        return;
    }

    const float* s; u16* d;
    int R, C, lds_, ldo, Rpad, Cpad;
    if (z < 4)      { s = W_relu + 360000L * z; d = w2t + 384000L * z;
                      R = 600; C = 600; lds_ = 600; ldo = 640;  Rpad = 640; Cpad = 600; }
    else if (z == 4){ s = W_lin;           d = wlt;
                      R = 600; C = 600; lds_ = 600; ldo = 640;  Rpad = 640; Cpad = 640; }
    else if (z == 5){ s = W_sig;           d = wst;
                      R = 600; C = 600; lds_ = 600; ldo = 1280; Rpad = 640; Cpad = 600; }
    else if (z == 6){ s = W_sig + 360000;  d = wst + 640;
                      R = 600; C = 600; lds_ = 600; ldo = 1280; Rpad = 640; Cpad = 600; }
    else if (z == 7){ s = W_ih;            d = wiht;
                      R = 600; C = H4;  lds_ = H4;  ldo = 1280; Rpad = 640; Cpad = H4; }
    else if (z == 8){ s = W_hh;            d = wiht + 640;
                      R = 600; C = H4;  lds_ = H4;  ldo = 1280; Rpad = 640; Cpad = H4; }
    else            { s = W_log;           d = wlogt;
                      R = 600; C = 700; lds_ = 700; ldo = 640;  Rpad = 640; Cpad = 704; }

    int r0 = bx * 32, c0 = by * 32;
    if (r0 >= Rpad || c0 >= Cpad) return;
    int tx = tid & 31, ty = tid >> 5;
    #pragma unroll
    for (int dy = 0; dy < 32; dy += 8) {
        int r = r0 + ty + dy, c = c0 + tx;
        t[ty + dy][tx] = (r < R && c < C) ? s[(long)r * lds_ + c] : 0.f;
    }
    __syncthreads();
    #pragma unroll
    for (int dy = 0; dy < 32; dy += 8) {
        int c = c0 + ty + dy, r = r0 + tx;
        if (r < Rpad && c < Cpad) d[(long)c * ldo + r] = f2h(t[tx][ty + dy]);
    }
}

// er (2 h per thread, uint loads) into scat cols 0:600 + zero pads; pad flag
__global__ __launch_bounds__(320) void gather_relu_k(
    const int* __restrict__ rec, const u16* __restrict__ Ph,
    const float* __restrict__ b_relu, u16* __restrict__ scat, float* __restrict__ pad)
{
    int row = blockIdx.x;
    int t = threadIdx.x;
    int r0 = rec[row * 4 + 0], r1 = rec[row * 4 + 1];
    int r2 = rec[row * 4 + 2], r3 = rec[row * 4 + 3];
    u16* srow = scat + (long)row * 1280;
    if (t < 300) {
        int h = t << 1;
        uint a0 = *(const uint*)&Ph[(long)r0 * H4 + h];
        uint a1 = *(const uint*)&Ph[(long)r1 * H4 + 600 + h];
        uint a2 = *(const uint*)&Ph[(long)r2 * H4 + 1200 + h];
        uint a3 = *(const uint*)&Ph[(long)r3 * H4 + 1800 + h];
        float lo = b_relu[h]     + h2f((u16)a0) + h2f((u16)a1) + h2f((u16)a2) + h2f((u16)a3);
        float hi = b_relu[h + 1] + h2f((u16)(a0 >> 16)) + h2f((u16)(a1 >> 16))
                                 + h2f((u16)(a2 >> 16)) + h2f((u16)(a3 >> 16));
        uint o = (uint)f2h(fmaxf(lo, 0.f)) | ((uint)f2h(fmaxf(hi, 0.f)) << 16);
        *(uint*)&srow[h] = o;
    } else {
        int i = t - 300;
        *(uint*)&srow[600 + (i << 1)]  = 0;
        *(uint*)&srow[1240 + (i << 1)] = 0;
    }
    if (t == 0) {
        int mx = max(max(r0, r1), max(r2, r3));
        pad[row] = (mx == 0) ? 1.f : 0.f;
    }
}

// ---------------------------------------------------------------------------
// R8 post4_k: MERGED softmax (blocks 0..5599) + erT transpose (5600..18975).
// Softmax upgrade: the per-batch column mask pad[b][0:700] is IDENTICAL for
// all 700 rows; old kernel re-read it per element (63 MB of scattered L2
// loads + compares). Now staged once per block into LDS (3 coalesced loads
// per thread), per-element check reads LDS (2-way bank alias = free, m136).
// Transpose task: verbatim erT body (was transpz_k). Merging removes one
// launch gap and lets the two memory-bound phases overlap on the CUs.
// ---------------------------------------------------------------------------
__global__ __launch_bounds__(256) void post4_k(
    u16* __restrict__ attnh, const float* __restrict__ pad,
    const u16* __restrict__ scat, u16* __restrict__ erT)
{
    __shared__ float smem[1056];          // union: pad mask [704] | transpose [32][33]
    const int bidf = blockIdx.x;
    const int tid  = threadIdx.x;

    if (bidf < 5600) {
        // ---- masked softmax, wave-per-row, pad mask in LDS ----
        const int bx = bidf % 175, b = bidf / 175;
        const float* pb = pad + b * LL;
        for (int e = tid; e < 704; e += 256)
            smem[e] = (e < LL) ? pb[e] : 1.f;       // cols >=700 marked padded
        __syncthreads();

        const int wave = tid >> 6, lane = tid & 63;
        const int l = bx * 4 + wave;
        u16* row = attnh + (long)b * (LL * 704) + (long)l * 704;
        const bool rowpad = smem[l] != 0.f;

        float v[12];
        float mx = -INFINITY;
        #pragma unroll
        for (int i = 0; i < 6; ++i) {
            int e0 = (lane + (i << 6)) << 1;
            float x0 = -INFINITY, x1 = -INFINITY;
            if (e0 < 704) {
                uint u = *(const uint*)&row[e0];
                if (!(rowpad || e0 == l || smem[e0] != 0.f)) x0 = h2f((u16)u);
                int e1 = e0 + 1;
                if (!(rowpad || e1 == l || smem[e1] != 0.f)) x1 = h2f((u16)(u >> 16));
            }
            v[2 * i] = x0;  v[2 * i + 1] = x1;
            mx = fmaxf(mx, fmaxf(x0, x1));
        }
        #pragma unroll
        for (int m = 32; m > 0; m >>= 1) mx = fmaxf(mx, __shfl_xor(mx, m));
        mx = fmaxf(mx, -1e30f);

        float sum = 0.f;
        #pragma unroll
        for (int i = 0; i < 12; ++i) { v[i] = expf(v[i] - mx); sum += v[i]; }
        #pragma unroll
        for (int m = 32; m > 0; m >>= 1) sum += __shfl_xor(sum, m);
        float inv = (sum > 0.f) ? 1.f / sum : 0.f;

        #pragma unroll
        for (int i = 0; i < 6; ++i) {
            int e0 = (lane + (i << 6)) << 1;
            if (e0 < 704) {
                uint u = (uint)f2h(v[2 * i] * inv) | ((uint)f2h(v[2 * i + 1] * inv) << 16);
                *(uint*)&row[e0] = u;
            }
        }
    } else {
        // ---- erT[b][h][l] transpose: scat er cols -> [600][704] rows ----
        int tt = bidf - 5600;
        const int bx = tt % 22;  tt /= 22;
        const int by = tt % 19;
        const int bz = tt / 19;
        float (*tr)[33] = (float(*)[33])smem;
        const u16* s = scat + (long)LL * 1280 * bz;
        u16* d = erT + (long)HH * 704 * bz;
        int r0 = bx * 32, c0 = by * 32;
        int tx = tid & 31, ty = tid >> 5;
        #pragma unroll
        for (int dy = 0; dy < 32; dy += 8) {
            int r = r0 + ty + dy, c = c0 + tx;
            tr[ty + dy][tx] = (r < LL && c < HH) ? h2f(s[(long)r * 1280 + c]) : 0.f;
        }
        __syncthreads();
        #pragma unroll
        for (int dy = 0; dy < 32; dy += 8) {
            int c = c0 + ty + dy, r = r0 + tx;
            if (r < 704 && c < HH) d[(long)c * 704 + r] = f2h(tr[tx][ty + dy]);
        }
    }
}

// fused xcat: x-gather (bx==3) + xmean finalize (bx<3) -> f16 xcat halves
__global__ __launch_bounds__(256) void xcat_k(const u16* __restrict__ sc,
                                              const int* __restrict__ index,
                                              const float* __restrict__ xmean,
                                              u16* __restrict__ xcat)
{
    int b = blockIdx.y;
    if (blockIdx.x == 3) {
        const u16* src = sc + ((long)b * LL + index[b]) * HH;
        u16* dst = xcat + b * 1280;
        for (int j = threadIdx.x; j < 1280; j += 256) {
            if (j < 600) dst[j] = src[j];
            else if (j < 640) dst[j] = 0;
            else if (j >= 1240) dst[j] = 0;
        }
        return;
    }
    int h = blockIdx.x * 256 + threadIdx.x;
    if (h >= HH) return;
    xcat[b * 1280 + 640 + h] = f2h(xmean[b * 640 + h] * (1.f / 700.f));
}

// cell = sigmoid(i)*tanh(g); hidden = sigmoid(o)*tanh(cell); + f16 hidden copy
__global__ void lstm_act_k(const float* __restrict__ gates,
                           float* __restrict__ out_hid, float* __restrict__ out_cell,
                           u16* __restrict__ hid16)
{
    int h = blockIdx.x * 256 + threadIdx.x;
    int b = blockIdx.y;
    if (h >= 640) return;
    if (h >= HH) { hid16[b * 640 + h] = 0; return; }
    const float* g = gates + b * H4;
    float gi = g[h], gg = g[1200 + h], go = g[1800 + h];
    float c = (1.f / (1.f + expf(-gi))) * tanhf(gg);
    float hd = (1.f / (1.f + expf(-go))) * tanhf(c);
    out_hid[b * HH + h] = hd;
    out_cell[b * HH + h] = c;
    hid16[b * 640 + h] = f2h(hd);
}

// masked log-softmax of glog row -> out
__global__ __launch_bounds__(256) void logsoftmax_k(const float* __restrict__ glog,
                                                    const float* __restrict__ pad,
                                                    const int* __restrict__ index,
                                                    float* __restrict__ out)
{
    int b = blockIdx.x;
    int t = threadIdx.x;
    int idx = index[b];
    __shared__ float red[256];
    float v[3];
    float mx = -INFINITY;
    #pragma unroll
    for (int ii = 0; ii < 3; ++ii) {
        int l = ii * 256 + t;
        float x = -INFINITY;
        if (l < LL && !(pad[b * LL + l] != 0.f || l == idx)) x = glog[b * 704 + l];
        v[ii] = x;
        mx = fmaxf(mx, x);
    }
    red[t] = mx; __syncthreads();
    for (int s = 128; s > 0; s >>= 1) {
        if (t < s) red[t] = fmaxf(red[t], red[t + s]);
        __syncthreads();
    }
    mx = red[0]; __syncthreads();
    float sum = 0.f;
    #pragma unroll
    for (int ii = 0; ii < 3; ++ii) {
        int l = ii * 256 + t;
        if (l < LL) sum += expf(v[ii] - mx);
    }
    red[t] = sum; __syncthreads();
    for (int s = 128; s > 0; s >>= 1) {
        if (t < s) red[t] += red[t + s];
        __syncthreads();
    }
    float lse = mx + logf(red[0]);
    #pragma unroll
    for (int ii = 0; ii < 3; ++ii) {
        int l = ii * 256 + t;
        if (l < LL) out[b * LL + l] = fmaxf(v[ii] - lse, -1e30f);
    }
}

// ---------------------------------------------------------------------------
extern "C" void kernel_launch(void* const* d_in, const int* in_sizes, int n_in,
                              void* d_out, int out_size, void* d_ws, size_t ws_size,
                              hipStream_t stream)
{
    const int*   records = (const int*)d_in[0];
    const int*   index   = (const int*)d_in[1];
    const float* emb     = (const float*)d_in[2];
    const float* W_relu  = (const float*)d_in[3];
    const float* b_relu  = (const float*)d_in[4];
    const float* W_lin   = (const float*)d_in[5];
    const float* b_lin   = (const float*)d_in[6];
    const float* W_sig   = (const float*)d_in[7];
    const float* b_sig   = (const float*)d_in[8];
    const float* W_ih    = (const float*)d_in[9];
    const float* W_hh    = (const float*)d_in[10];
    const float* b_ih    = (const float*)d_in[11];
    const float* b_hh    = (const float*)d_in[12];
    const float* W_log   = (const float*)d_in[13];
    const float* b_log   = (const float*)d_in[14];

    char* ws = (char*)d_ws;
    u16*   scat   = (u16*)(ws + O_SCAT);
    u16*   linh   = (u16*)(ws + O_LINH);
    u16*   Ph     = (u16*)(ws + O_R1);
    u16*   sc16   = (u16*)(ws + O_R1);    // reuses Ph region after gather
    u16*   attnh  = (u16*)(ws + O_ATTNH);
    u16*   erT    = (u16*)(ws + O_ERT);
    u16*   embh   = (u16*)(ws + O_EMBH);
    u16*   w2t    = (u16*)(ws + O_W2T);
    u16*   wlt    = (u16*)(ws + O_WLT);
    u16*   wst    = (u16*)(ws + O_WST);
    float* bl640  = (float*)(ws + O_BL);
    float* pad    = (float*)(ws + O_PAD);
    float* gates  = (float*)(ws + O_GATES);
    u16*   wiht   = (u16*)(ws + O_WIHT);
    u16*   wlogt  = (u16*)(ws + O_WLOGT);
    u16*   xcat   = (u16*)(ws + O_XCAT);
    u16*   hid16  = (u16*)(ws + O_HID16);
    float* glog   = (float*)(ws + O_GLOG);
    float* xmean  = (float*)(ws + O_XMEAN);

    float* out      = (float*)d_out;
    float* out_attn = out;
    float* out_hid  = out + BB * LL;
    float* out_cell = out + BB * LL + BB * HH;

    // ---- all staging conversions + tail-C bias inits + xmean init ----
    prep_k<<<dim3(20, 75, 12), 256, 0, stream>>>(
        emb, W_relu, W_lin, W_sig, W_ih, W_hh, W_log, b_lin, b_ih, b_hh, b_log,
        embh, w2t, wlt, wst, wiht, wlogt, bl640, gates, glog, xmean);

    // K1: Ph[2000][2400] = embh @ w2t^T  (Kp=640)
    hgemm_v2<1><<<dim3(19, 16, 1), 512, 0, stream>>>(
        embh, w2t, Ph, nullptr, nullptr, 0, nullptr,
        VV, H4, 640, 640, 640, H4, 0L, 0L, 0L);

    // K2: gather + relu -> scat er cols (+pads), pad flags
    gather_relu_k<<<dim3(BB * LL), 320, 0, stream>>>(records, Ph, b_relu, scat, pad);

    // K3: linh = f16(er @ W_lin + b_lin)  (Kp=640, N=640)
    hgemm_v2<1><<<dim3(5, 175, 1), 512, 0, stream>>>(
        scat, wlt, linh, bl640, nullptr, 0, nullptr,
        BB * LL, 640, 640, 1280, 640, 640, 0L, 0L, 0L);

    // K4: attnh[b] = f16(lin[b] @ er[b]^T)  (Kp=640, stride-704 out)
    hgemm_v2<1><<<dim3(6, 6, BB), 512, 0, stream>>>(
        linh, scat, attnh, nullptr, nullptr, 0, nullptr,
        LL, LL, 640, 640, 1280, 704, (long)LL * 640, (long)LL * 1280, (long)LL * 704);

    // merged: softmax (LDS pad mask) + erT transpose, one launch
    post4_k<<<dim3(5600 + 22 * 19 * BB), 256, 0, stream>>>(attnh, pad, scat, erT);

    // K5: att = attnh[b] @ erT[b]^T -> scat cols 640:1240  (Kp=704)
    hgemm_v2<1><<<dim3(5, 6, BB), 512, 0, stream>>>(
        attnh, erT, scat + 640, nullptr, nullptr, 0, nullptr,
        LL, HH, 704, 704, 704, 1280, (long)LL * 704, (long)HH * 704, (long)LL * 1280);

    // K6: sc16 = f16(sigmoid([er|att] @ wst^T + b_sig) * er)  (Kp=1280)
    //     + fused xmean column-sums
    hgemm_v2<2><<<dim3(5, 175, 1), 512, 0, stream>>>(
        scat, wst, sc16, b_sig, scat, 1280, xmean,
        BB * LL, HH, 1280, 1280, 1280, 600, 0L, 0L, 0L);

    // tail: xcat (gather + xmean finalize), skinny split-K GEMMs
    xcat_k<<<dim3(4, BB), 256, 0, stream>>>(sc16, index, xmean, xcat);
    sgemm_k<<<dim3(38, 5), 256, 0, stream>>>(
        xcat, wiht, gates, H4, 256, 1280, 1280, H4);
    lstm_act_k<<<dim3(3, BB), 256, 0, stream>>>(gates, out_hid, out_cell, hid16);
    sgemm_k<<<dim3(11, 5), 256, 0, stream>>>(
        hid16, wlogt, glog, LL, 128, 640, 640, 704);
    logsoftmax_k<<<dim3(BB), 256, 0, stream>>>(glog, pad, index, out_attn);
}